// Round 9
// baseline (65.574 us; speedup 1.0000x reference)
//
#include <hip/hip_runtime.h>
#include <math.h>

#define NAG 64
#define ZD  512
#define DM  512

typedef float f32x4 __attribute__((ext_vector_type(4)));

// ---------------------------------------------------------------------------
// Kernel A: batched per-agent GEMV for Q, K, V.
// R2's simple high-occupancy structure (6144 blocks x 4 waves, 4 rows/wave),
// but all W traffic is NON-TEMPORAL: W is a 201 MB read-once stream that was
// thrashing the 256 MB L3 every replay (steady-state FETCH_SIZE = 99 MB =
// half the stream re-missing). Evict-first W loads keep the L3 out of the
// way so HBM streams clean. nontemporal builtin needs clang ext-vector
// pointers (HIP_vector_type float4* is rejected) -> f32x4.
// ---------------------------------------------------------------------------
__global__ __launch_bounds__(256) void qkv_gemv_kernel(
    const float* __restrict__ z,
    const float* __restrict__ Wq,
    const float* __restrict__ Wk,
    const float* __restrict__ Wv,
    float* __restrict__ Q, float* __restrict__ K, float* __restrict__ V)
{
    const int wave = threadIdx.x >> 6;
    const int lane = threadIdx.x & 63;
    const int rowBase = blockIdx.x * 16 + wave * 4;   // in [0, 3*64*512)
    const int m   = rowBase >> 15;                    // matrix select
    const int rem = rowBase & 32767;
    const int n   = rem >> 9;                         // agent
    const int d0  = rem & 511;                        // first output row

    const float* __restrict__ W = (m == 0) ? Wq : ((m == 1) ? Wk : Wv);
    float* __restrict__ O       = (m == 0) ? Q  : ((m == 1) ? K  : V);

    const float* zr = z + n * ZD;
    const f32x4 zA = *reinterpret_cast<const f32x4*>(zr + lane * 4);
    const f32x4 zB = *reinterpret_cast<const f32x4*>(zr + 256 + lane * 4);

    const float* Wbase = W + ((size_t)(n * DM + d0)) * ZD;
    float acc[4];
#pragma unroll
    for (int r = 0; r < 4; ++r) {
        const float* wr = Wbase + (size_t)r * ZD;
        const f32x4 a = __builtin_nontemporal_load(
            reinterpret_cast<const f32x4*>(wr + lane * 4));
        const f32x4 b = __builtin_nontemporal_load(
            reinterpret_cast<const f32x4*>(wr + 256 + lane * 4));
        acc[r] = a[0]*zA[0] + a[1]*zA[1] + a[2]*zA[2] + a[3]*zA[3]
               + b[0]*zB[0] + b[1]*zB[1] + b[2]*zB[2] + b[3]*zB[3];
    }
    float a0 = acc[0], a1 = acc[1], a2 = acc[2], a3 = acc[3];
#pragma unroll
    for (int off = 32; off > 0; off >>= 1) {
        a0 += __shfl_down(a0, off);
        a1 += __shfl_down(a1, off);
        a2 += __shfl_down(a2, off);
        a3 += __shfl_down(a3, off);
    }
    if (lane == 0)
        *reinterpret_cast<float4*>(O + n * DM + d0) = make_float4(a0, a1, a2, a3);
}

// ---------------------------------------------------------------------------
// Kernel B+C+D fused: blocks [0,64) attention+messages for receiver j;
// blocks [64,576) infer-loss partial for output-dim zp = blk-64; the LAST
// infer block to finish (device atomic counter, memset to 0 per call) folds
// the 512 partials into the scalar loss.
// ---------------------------------------------------------------------------
__global__ __launch_bounds__(256) void attn_infer_kernel(
    const float* __restrict__ Q, const float* __restrict__ K,
    const float* __restrict__ V, const float* __restrict__ Wi,
    const float* __restrict__ bi, const float* __restrict__ z,
    float* __restrict__ out, float* __restrict__ zp_partial,
    unsigned int* __restrict__ counter)
{
    __shared__ __align__(16) float sbuf[DM];
    __shared__ float Sc[NAG];
    __shared__ float Al[NAG];
    __shared__ int is_last;
    const int t = threadIdx.x;

    if (blockIdx.x < NAG) {
        // ---------------- attention + messages, receiver j ----------------
        const int j = blockIdx.x;
        sbuf[t]       = Q[j * DM + t];
        sbuf[t + 256] = Q[j * DM + t + 256];
        __syncthreads();

        const int i = t >> 2;
        const int c = t & 3;
        const float* Krow = K + i * DM + c * 128;
        const float* Qsub = sbuf + c * 128;
        float p = 0.f;
#pragma unroll
        for (int k = 0; k < 32; ++k) {
            float4 kv = *reinterpret_cast<const float4*>(Krow + k * 4);
            float4 qv = *reinterpret_cast<const float4*>(Qsub + k * 4);
            p += kv.x*qv.x + kv.y*qv.y + kv.z*qv.z + kv.w*qv.w;
        }
        p += __shfl_xor(p, 1);
        p += __shfl_xor(p, 2);
        if (c == 0)
            Sc[i] = (i == j) ? -INFINITY : p * 0.044194173824159216f; // 1/sqrt(512)
        __syncthreads();

        if (t < 64) {
            float s = Sc[t];
            float mx = s;
#pragma unroll
            for (int off = 32; off > 0; off >>= 1) mx = fmaxf(mx, __shfl_xor(mx, off));
            float e = expf(s - mx);           // exp(-inf)=0 masks diagonal
            float sum = e;
#pragma unroll
            for (int off = 32; off > 0; off >>= 1) sum += __shfl_xor(sum, off);
            Al[t] = e / sum;
        }
        __syncthreads();

#pragma unroll
        for (int dd = 0; dd < 2; ++dd) {
            const int d = t + dd * 256;
            float acc = 0.f;
            for (int i2 = 0; i2 < NAG; ++i2) acc += Al[i2] * V[i2 * DM + d];
            out[j * DM + d] = acc;
        }
    } else {
        // ---------------- infer loss partial for output-dim zp ----------------
        const int zp = blockIdx.x - NAG;
        const float* wr = Wi + (size_t)zp * DM;
        sbuf[t]       = wr[t];
        sbuf[t + 256] = wr[t + 256];
        __syncthreads();

        const int i = t >> 2;
        const int c = t & 3;
        const float* Vrow = V + i * DM + c * 128;
        const float* Wsub = sbuf + c * 128;
        float p = 0.f;
#pragma unroll
        for (int k = 0; k < 32; ++k) {
            float4 vv = *reinterpret_cast<const float4*>(Vrow + k * 4);
            float4 wv = *reinterpret_cast<const float4*>(Wsub + k * 4);
            p += vv.x*wv.x + vv.y*wv.y + vv.z*wv.z + vv.w*wv.w;
        }
        p += __shfl_xor(p, 1);
        p += __shfl_xor(p, 2);

        float e2 = 0.f;
        if (c == 0) {
            float e = p + bi[zp] - z[i * ZD + zp];
            e2 = e * e;
        }
#pragma unroll
        for (int off = 32; off > 0; off >>= 1) e2 += __shfl_down(e2, off);

        const int wv2 = t >> 6;
        const int ln  = t & 63;
        if (ln == 0) Sc[wv2] = e2;
        __syncthreads();
        if (t == 0) {
            zp_partial[zp] = Sc[0] + Sc[1] + Sc[2] + Sc[3];
            __threadfence();                  // partial visible device-wide
            unsigned int old = atomicAdd(counter, 1u);
            is_last = (old == ZD - 1);
        }
        __syncthreads();

        // last infer block folds all 512 partials into the loss scalar
        if (is_last && t < 64) {
            __threadfence();
            volatile const float* vp = zp_partial;
            float v = 0.f;
#pragma unroll
            for (int k = 0; k < 8; ++k) v += vp[t + k * 64];
#pragma unroll
            for (int off = 32; off > 0; off >>= 1) v += __shfl_down(v, off);
            if (t == 0) out[NAG * DM] = v * (1.0f / (NAG * ZD));
        }
    }
}

extern "C" void kernel_launch(void* const* d_in, const int* in_sizes, int n_in,
                              void* d_out, int out_size, void* d_ws, size_t ws_size,
                              hipStream_t stream) {
    const float* z  = (const float*)d_in[0];
    const float* Wq = (const float*)d_in[1];
    const float* Wk = (const float*)d_in[2];
    const float* Wv = (const float*)d_in[3];
    const float* Wi = (const float*)d_in[4];
    const float* bi = (const float*)d_in[5];
    float* out = (float*)d_out;

    float* Q = (float*)d_ws;
    float* K = Q + NAG * DM;
    float* V = K + NAG * DM;
    float* partial = V + NAG * DM;                 // 512 floats
    unsigned int* counter = (unsigned int*)(partial + ZD);

    // counter must be 0 at every call (ws is poisoned once, never restored)
    (void)hipMemsetAsync(counter, 0, sizeof(unsigned int), stream);

    // 3 matrices * 64 agents * 512 rows / 16 rows per block = 6144 blocks
    hipLaunchKernelGGL(qkv_gemv_kernel, dim3(6144), dim3(256), 0, stream,
                       z, Wq, Wk, Wv, Q, K, V);
    hipLaunchKernelGGL(attn_infer_kernel, dim3(NAG + ZD), dim3(256), 0, stream,
                       Q, K, V, Wi, bi, z, out, partial, counter);
}

// Round 10
// 48.918 us; speedup vs baseline: 1.3405x; 1.3405x over previous
//
#include <hip/hip_runtime.h>
#include <math.h>

#define NAG 64
#define ZD  512
#define DM  512

typedef float f32x4 __attribute__((ext_vector_type(4)));

// ---------------------------------------------------------------------------
// Kernel A: batched per-agent GEMV for Q, K, V.
// Simple high-occupancy structure (6144 blocks x 4 waves, 4 rows/wave) with
// NON-TEMPORAL W loads: W is a 201 MB read-once stream that thrashes the
// 256 MB L3 on every replay (steady-state FETCH_SIZE = 99 MB = half the
// stream re-missing). Evict-first W loads keep the L3 out of the way.
// nontemporal builtin requires clang ext-vector pointers -> f32x4.
// ---------------------------------------------------------------------------
__global__ __launch_bounds__(256) void qkv_gemv_kernel(
    const float* __restrict__ z,
    const float* __restrict__ Wq,
    const float* __restrict__ Wk,
    const float* __restrict__ Wv,
    float* __restrict__ Q, float* __restrict__ K, float* __restrict__ V)
{
    const int wave = threadIdx.x >> 6;
    const int lane = threadIdx.x & 63;
    const int rowBase = blockIdx.x * 16 + wave * 4;   // in [0, 3*64*512)
    const int m   = rowBase >> 15;                    // matrix select
    const int rem = rowBase & 32767;
    const int n   = rem >> 9;                         // agent
    const int d0  = rem & 511;                        // first output row

    const float* __restrict__ W = (m == 0) ? Wq : ((m == 1) ? Wk : Wv);
    float* __restrict__ O       = (m == 0) ? Q  : ((m == 1) ? K  : V);

    const float* zr = z + n * ZD;
    const f32x4 zA = *reinterpret_cast<const f32x4*>(zr + lane * 4);
    const f32x4 zB = *reinterpret_cast<const f32x4*>(zr + 256 + lane * 4);

    const float* Wbase = W + ((size_t)(n * DM + d0)) * ZD;
    float acc[4];
#pragma unroll
    for (int r = 0; r < 4; ++r) {
        const float* wr = Wbase + (size_t)r * ZD;
        const f32x4 a = __builtin_nontemporal_load(
            reinterpret_cast<const f32x4*>(wr + lane * 4));
        const f32x4 b = __builtin_nontemporal_load(
            reinterpret_cast<const f32x4*>(wr + 256 + lane * 4));
        acc[r] = a[0]*zA[0] + a[1]*zA[1] + a[2]*zA[2] + a[3]*zA[3]
               + b[0]*zB[0] + b[1]*zB[1] + b[2]*zB[2] + b[3]*zB[3];
    }
    float a0 = acc[0], a1 = acc[1], a2 = acc[2], a3 = acc[3];
#pragma unroll
    for (int off = 32; off > 0; off >>= 1) {
        a0 += __shfl_down(a0, off);
        a1 += __shfl_down(a1, off);
        a2 += __shfl_down(a2, off);
        a3 += __shfl_down(a3, off);
    }
    if (lane == 0)
        *reinterpret_cast<float4*>(O + n * DM + d0) = make_float4(a0, a1, a2, a3);
}

// ---------------------------------------------------------------------------
// Kernel B+C fused: blocks [0,64) attention+messages for receiver j;
// blocks [64,576) infer-loss partial for output-dim zp = blk-64.
// ---------------------------------------------------------------------------
__global__ __launch_bounds__(256) void attn_infer_kernel(
    const float* __restrict__ Q, const float* __restrict__ K,
    const float* __restrict__ V, const float* __restrict__ Wi,
    const float* __restrict__ bi, const float* __restrict__ z,
    float* __restrict__ out, float* __restrict__ zp_partial)
{
    __shared__ __align__(16) float sbuf[DM];
    __shared__ float Sc[NAG];
    __shared__ float Al[NAG];
    const int t = threadIdx.x;

    if (blockIdx.x < NAG) {
        const int j = blockIdx.x;
        sbuf[t]       = Q[j * DM + t];
        sbuf[t + 256] = Q[j * DM + t + 256];
        __syncthreads();

        const int i = t >> 2;
        const int c = t & 3;
        const float* Krow = K + i * DM + c * 128;
        const float* Qsub = sbuf + c * 128;
        float p = 0.f;
#pragma unroll
        for (int k = 0; k < 32; ++k) {
            float4 kv = *reinterpret_cast<const float4*>(Krow + k * 4);
            float4 qv = *reinterpret_cast<const float4*>(Qsub + k * 4);
            p += kv.x*qv.x + kv.y*qv.y + kv.z*qv.z + kv.w*qv.w;
        }
        p += __shfl_xor(p, 1);
        p += __shfl_xor(p, 2);
        if (c == 0)
            Sc[i] = (i == j) ? -INFINITY : p * 0.044194173824159216f; // 1/sqrt(512)
        __syncthreads();

        if (t < 64) {
            float s = Sc[t];
            float mx = s;
#pragma unroll
            for (int off = 32; off > 0; off >>= 1) mx = fmaxf(mx, __shfl_xor(mx, off));
            float e = expf(s - mx);           // exp(-inf)=0 masks diagonal
            float sum = e;
#pragma unroll
            for (int off = 32; off > 0; off >>= 1) sum += __shfl_xor(sum, off);
            Al[t] = e / sum;
        }
        __syncthreads();

#pragma unroll
        for (int dd = 0; dd < 2; ++dd) {
            const int d = t + dd * 256;
            float acc = 0.f;
            for (int i2 = 0; i2 < NAG; ++i2) acc += Al[i2] * V[i2 * DM + d];
            out[j * DM + d] = acc;
        }
    } else {
        const int zp = blockIdx.x - NAG;
        const float* wr = Wi + (size_t)zp * DM;
        sbuf[t]       = wr[t];
        sbuf[t + 256] = wr[t + 256];
        __syncthreads();

        const int i = t >> 2;
        const int c = t & 3;
        const float* Vrow = V + i * DM + c * 128;
        const float* Wsub = sbuf + c * 128;
        float p = 0.f;
#pragma unroll
        for (int k = 0; k < 32; ++k) {
            float4 vv = *reinterpret_cast<const float4*>(Vrow + k * 4);
            float4 wv = *reinterpret_cast<const float4*>(Wsub + k * 4);
            p += vv.x*wv.x + vv.y*wv.y + vv.z*wv.z + vv.w*wv.w;
        }
        p += __shfl_xor(p, 1);
        p += __shfl_xor(p, 2);

        float e2 = 0.f;
        if (c == 0) {
            float e = p + bi[zp] - z[i * ZD + zp];
            e2 = e * e;
        }
#pragma unroll
        for (int off = 32; off > 0; off >>= 1) e2 += __shfl_down(e2, off);

        const int wv2 = t >> 6;
        const int ln  = t & 63;
        if (ln == 0) Sc[wv2] = e2;
        __syncthreads();
        if (t == 0) zp_partial[zp] = Sc[0] + Sc[1] + Sc[2] + Sc[3];
    }
}

// ---------------------------------------------------------------------------
// Kernel D: fold the 512 per-zp partials into the scalar loss.
// ---------------------------------------------------------------------------
__global__ __launch_bounds__(64) void loss_reduce_kernel(
    const float* __restrict__ zp_partial, float* __restrict__ out)
{
    float v = 0.f;
#pragma unroll
    for (int k = 0; k < 8; ++k) v += zp_partial[threadIdx.x + k * 64];
#pragma unroll
    for (int off = 32; off > 0; off >>= 1) v += __shfl_down(v, off);
    if (threadIdx.x == 0) out[NAG * DM] = v * (1.0f / (NAG * ZD));
}

extern "C" void kernel_launch(void* const* d_in, const int* in_sizes, int n_in,
                              void* d_out, int out_size, void* d_ws, size_t ws_size,
                              hipStream_t stream) {
    const float* z  = (const float*)d_in[0];
    const float* Wq = (const float*)d_in[1];
    const float* Wk = (const float*)d_in[2];
    const float* Wv = (const float*)d_in[3];
    const float* Wi = (const float*)d_in[4];
    const float* bi = (const float*)d_in[5];
    float* out = (float*)d_out;

    float* Q = (float*)d_ws;
    float* K = Q + NAG * DM;
    float* V = K + NAG * DM;
    float* partial = V + NAG * DM;   // 512 floats

    // 3 matrices * 64 agents * 512 rows / 16 rows per block = 6144 blocks
    hipLaunchKernelGGL(qkv_gemv_kernel, dim3(6144), dim3(256), 0, stream,
                       z, Wq, Wk, Wv, Q, K, V);
    hipLaunchKernelGGL(attn_infer_kernel, dim3(NAG + ZD), dim3(256), 0, stream,
                       Q, K, V, Wi, bi, z, out, partial);
    hipLaunchKernelGGL(loss_reduce_kernel, dim3(1), dim3(64), 0, stream,
                       partial, out);
}